// Round 2
// baseline (386.917 us; speedup 1.0000x reference)
//
#include <hip/hip_runtime.h>
#include <math.h>

// Fast guided filter, fully fused, FP64 internal math (fp64 margin vs fp32 ref
// is what keeps absmax at the passing 1.0 -> do NOT reduce precision).
// Round-5: identical to round-4 (bench infra failed; no counter evidence).
//   1. Stage 2 separable: vertical column sums (Sx,Sy,Sxy,Sxx) -> LDS planes,
//      then horizontal finish. ~54 -> ~36 fp64-pipe ops per A-point (cvt once
//      per element instead of once per tap). A/b planes alias the dead
//      vertical-sum planes across a barrier (LDS 50KB, 3 blocks/CU).
//   2. Stage 3 rolling pair-sums: per column window keep {c0+c1, c1+c2, full3}
//      at the three vertical levels (t/m/p). The 8 directional sums are then
//      direct state reads (L/R need 1 add each); weight folds into the 2nd fma:
//      d = fma(w, fma(S_A, im, S_B), -im). Advance = 6 adds/side.
//   3. Argmin keeps only best_d: fabs(d) < fabs(best) folds into v_cmp_f64
//      abs input modifiers (no explicit best_ad chain).
// Net fp64-pipe ops ~169k -> ~106k per block (-37%).

#define TX 64
#define TY 16
#define SW (TX + 4)   // 68
#define SH (TY + 4)   // 20
#define AW (TX + 2)   // 66
#define AH (TY + 2)   // 18
#define NT 256

#define NA (AH * AW)          // 1188 A-points
#define NV (AH * SW)          // 1224 vertical-sum points
#define NS (SH * SW)          // 1360 staged input points
#define ITER_A ((NA + NT - 1) / NT)   // 5

__device__ __forceinline__ double fast_rcp(double v) {
#if __has_builtin(__builtin_amdgcn_rcp)
    double r = __builtin_amdgcn_rcp(v);     // v_rcp_f64, ~29-bit
#else
    double r = 1.0 / v;
#endif
    double e = fma(-v, r, 1.0);             // Newton 1 -> ~53-bit
    r = fma(r, e, r);
    e = fma(-v, r, 1.0);                    // Newton 2 -> ~1 ulp
    r = fma(r, e, r);
    return r;
}

__global__ __launch_bounds__(NT) void fgf_fused_kernel(
    const float* __restrict__ x, const float* __restrict__ y,
    float* __restrict__ out, int H, int W)
{
    __shared__ float  sxs[SH][SW];
    __shared__ float  sys[SH][SW];
    // planes: 0=Sx, 1=Sy, 2=Sxy, 3=Sxx  (vertical 3-row sums)
    // after stage 2b, planes 0/1 are reused (post-barrier) as A and b.
    __shared__ double sV[4][AH][SW];

    const int c   = blockIdx.z;
    const int ox0 = blockIdx.x * TX;
    const int oy0 = blockIdx.y * TY;
    const size_t plane = (size_t)H * (size_t)W;
    const float* xc = x + (size_t)c * plane;
    const float* yc = y + (size_t)c * plane;

    const int tid = threadIdx.y * 64 + threadIdx.x;

    // ---- stage 1: inputs with replicate clamp (box filter uses edge pad) ----
    for (int i = tid; i < NS; i += NT) {
        int ly = i / SW, lx = i - ly * SW;
        int gy = oy0 - 2 + ly;
        int gx = ox0 - 2 + lx;
        gy = gy < 0 ? 0 : (gy >= H ? H - 1 : gy);
        gx = gx < 0 ? 0 : (gx >= W ? W - 1 : gx);
        size_t gidx = (size_t)gy * W + gx;
        sxs[ly][lx] = xc[gidx];
        sys[ly][lx] = yc[gidx];
    }
    __syncthreads();

    // ---- stage 2a: vertical 3-row column sums (cvt once per element) ----
    for (int i = tid; i < NV; i += NT) {
        int ly = i / SW, lx = i - ly * SW;
        double x0 = (double)sxs[ly + 0][lx];
        double x1 = (double)sxs[ly + 1][lx];
        double x2 = (double)sxs[ly + 2][lx];
        double y0 = (double)sys[ly + 0][lx];
        double y1 = (double)sys[ly + 1][lx];
        double y2 = (double)sys[ly + 2][lx];
        sV[0][ly][lx] = (x0 + x1) + x2;
        sV[1][ly][lx] = (y0 + y1) + y2;
        sV[2][ly][lx] = fma(x2, y2, fma(x1, y1, x0 * y0));
        sV[3][ly][lx] = fma(x2, x2, fma(x1, x1, x0 * x0));
    }
    __syncthreads();

    // ---- stage 2b: horizontal finish -> A,b in regs; then alias-write ----
    const double EPS81 = 81.0 * 1.0e-4;
    const double INV9  = 1.0 / 9.0;
    double Abuf[ITER_A], Bbuf[ITER_A];
#pragma unroll
    for (int it = 0; it < ITER_A; it++) {
        int i = tid + it * NT;
        double Av = 0.0, Bv = 0.0;
        if (i < NA) {
            int ly = i / AW, lx = i - ly * AW;
            int ay = oy0 - 1 + ly;
            int ax = ox0 - 1 + lx;
            if (ay >= 0 && ay < H && ax >= 0 && ax < W) {
                double Sx  = (sV[0][ly][lx] + sV[0][ly][lx + 1]) + sV[0][ly][lx + 2];
                double Sy  = (sV[1][ly][lx] + sV[1][ly][lx + 1]) + sV[1][ly][lx + 2];
                double Sxy = (sV[2][ly][lx] + sV[2][ly][lx + 1]) + sV[2][ly][lx + 2];
                double Sxx = (sV[3][ly][lx] + sV[3][ly][lx + 1]) + sV[3][ly][lx + 2];
                double num = fma(9.0, Sxy, -(Sx * Sy));            // 9*cov*9
                double den = fma(-Sx, Sx, fma(9.0, Sxx, EPS81));   // 9*(var+eps)*9
                Av = num * fast_rcp(den);
                Bv = fma(-Av, Sx, Sy) * INV9;
            }
        }
        Abuf[it] = Av;
        Bbuf[it] = Bv;
    }
    __syncthreads();   // all reads of sV done before we overwrite planes 0/1
#pragma unroll
    for (int it = 0; it < ITER_A; it++) {
        int i = tid + it * NT;
        if (i < NA) {
            int ly = i / AW, lx = i - ly * AW;
            sV[0][ly][lx] = Abuf[it];   // A
            sV[1][ly][lx] = Bbuf[it];   // b
        }
    }
    __syncthreads();

    double (*sA)[SW] = sV[0];
    double (*sB)[SW] = sV[1];

    // ---- stage 3: rolling pair-sum sliding window + argmin (fp64) ----
    // State per side: {L2=c0+c1, R2=c1+c2, F3=all3} at vertical levels
    //   t = A rows r-1..r, m = rows r..r+1, p = row r+1 (A-local r, r+1, r+2).
    // Directions: L=tL+pL, R=tR+pR, U=tF, D=mF, NW=tL, NE=tR, SW=mL, SE=mR.
    const double I6 = 1.0 / 6.0;
    const int tx = threadIdx.x;          // 0..63
    const int g  = threadIdx.y;          // 0..3
    const int r0 = g * 4;
    const int xg = ox0 + tx;
    const bool xok = (xg < W);

    double tLA, tRA, tFA, mLA, mRA, mFA, pLA, pRA, pFA;
    double tLB, tRB, tFB, mLB, mRB, mFB, pLB, pRB, pFB;
    {
        double a0 = sA[r0 + 0][tx], a1 = sA[r0 + 0][tx + 1], a2 = sA[r0 + 0][tx + 2];
        double L0 = a0 + a1, R0 = a1 + a2, F0 = L0 + a2;
        a0 = sA[r0 + 1][tx]; a1 = sA[r0 + 1][tx + 1]; a2 = sA[r0 + 1][tx + 2];
        double L1 = a0 + a1, R1 = a1 + a2, F1 = L1 + a2;
        a0 = sA[r0 + 2][tx]; a1 = sA[r0 + 2][tx + 1]; a2 = sA[r0 + 2][tx + 2];
        double L2 = a0 + a1, R2 = a1 + a2, F2 = L2 + a2;
        tLA = L0 + L1; tRA = R0 + R1; tFA = F0 + F1;
        mLA = L1 + L2; mRA = R1 + R2; mFA = F1 + F2;
        pLA = L2; pRA = R2; pFA = F2;

        double b0 = sB[r0 + 0][tx], b1 = sB[r0 + 0][tx + 1], b2 = sB[r0 + 0][tx + 2];
        double M0 = b0 + b1, S0 = b1 + b2, G0 = M0 + b2;
        b0 = sB[r0 + 1][tx]; b1 = sB[r0 + 1][tx + 1]; b2 = sB[r0 + 1][tx + 2];
        double M1 = b0 + b1, S1 = b1 + b2, G1 = M1 + b2;
        b0 = sB[r0 + 2][tx]; b1 = sB[r0 + 2][tx + 1]; b2 = sB[r0 + 2][tx + 2];
        double M2 = b0 + b1, S2 = b1 + b2, G2 = M2 + b2;
        tLB = M0 + M1; tRB = S0 + S1; tFB = G0 + G1;
        mLB = M1 + M2; mRB = S1 + S2; mFB = G1 + G2;
        pLB = M2; pRB = S2; pFB = G2;
    }

#pragma unroll
    for (int step = 0; step < 4; step++) {
        const int r  = r0 + step;
        const int yg = oy0 + r;
        if (xok && yg < H) {
            double im  = (double)sxs[r + 2][tx + 2];
            double mim = -im;

            // direction sums, order: L, R, U, D, NW, NE, SW, SE
            double sa[8] = { tLA + pLA, tRA + pRA, tFA, mFA, tLA, tRA, mLA, mRA };
            double sb[8] = { tLB + pLB, tRB + pRB, tFB, mFB, tLB, tRB, mLB, mRB };

            double best = 0.0;
#pragma unroll
            for (int k = 0; k < 8; k++) {
                double w = (k < 4) ? I6 : 0.25;
                double d = fma(w, fma(sa[k], im, sb[k]), mim);
                if (k == 0) best = d;
                else        best = (fabs(d) < fabs(best)) ? d : best;   // first-min tie order
            }

            double res = trunc(best + im);
            res = fmin(fmax(res, 0.0), 255.0);
            out[(size_t)c * plane + (size_t)yg * W + xg] = (float)res;
        }

        if (step < 3) {
            // advance: new A-local row r+3; t <- m, m <- p + n, p <- n
            double n0 = sA[r + 3][tx], n1 = sA[r + 3][tx + 1], n2 = sA[r + 3][tx + 2];
            double nL = n0 + n1, nR = n1 + n2, nF = nL + n2;
            tLA = mLA; tRA = mRA; tFA = mFA;
            mLA = pLA + nL; mRA = pRA + nR; mFA = pFA + nF;
            pLA = nL; pRA = nR; pFA = nF;

            n0 = sB[r + 3][tx]; n1 = sB[r + 3][tx + 1]; n2 = sB[r + 3][tx + 2];
            nL = n0 + n1; nR = n1 + n2; nF = nL + n2;
            tLB = mLB; tRB = mRB; tFB = mFB;
            mLB = pLB + nL; mRB = pRB + nR; mFB = pFB + nF;
            pLB = nL; pRB = nR; pFB = nF;
        }
    }
}

extern "C" void kernel_launch(void* const* d_in, const int* in_sizes, int n_in,
                              void* d_out, int out_size, void* d_ws, size_t ws_size,
                              hipStream_t stream) {
    const float* lr_x = (const float*)d_in[0];
    const float* lr_y = (const float*)d_in[1];
    // d_in[2] (hr_x) is dead in the reference computation.
    float* out = (float*)d_out;

    const int plane = in_sizes[0] / 3;
    const int H = (int)(0.5 + sqrt((double)plane));
    const int W = plane / H;

    dim3 block(64, 4, 1);
    dim3 grid((W + TX - 1) / TX, (H + TY - 1) / TY, 3);
    fgf_fused_kernel<<<grid, block, 0, stream>>>(lr_x, lr_y, out, H, W);
}

// Round 3
// 345.559 us; speedup vs baseline: 1.1197x; 1.1197x over previous
//
#include <hip/hip_runtime.h>
#include <math.h>

// Fast guided filter, fully fused, FP64 internal math (fp64 margin vs fp32 ref
// is what keeps absmax at the passing 1.0 -> do NOT reduce precision).
// Round-6 changes vs round-5 (kernel 136.9us, VALUBusy 48%, Occupancy 32%,
// HBM 13.6% -> latency/occupancy-bound, NOT ALU-bound):
//   1. Dropped sxs/sys LDS staging: stage 2a reads x/y straight from global
//      with replicate clamp (3x vertical re-read lands in L1; tile ~11KB),
//      'im' pixels preloaded into registers at kernel start (coalesced).
//      Removes 10.9KB LDS + one barrier (4 -> 3).
//   2. TY 16 -> 8: sV = 4*10*68*8B = 21,760B -> 7 blocks/CU = 28 waves/CU
//      (was 3 blocks / 12 waves). ~11% more stage-2 halo work traded for
//      2.3x concurrency; __launch_bounds__(256,7) caps VGPR at 73 (had 68).
//   3. Stage 3 unchanged rolling pair-sum window, now 2 rows/thread.

#define TX 64
#define TY 8
#define SW (TX + 4)   // 68 vertical-sum columns
#define AH (TY + 2)   // 10 A rows
#define AW (TX + 2)   // 66 A columns
#define NT 256
#define STEPS 2       // output rows per thread (TY / blockDim.y)

#define NV (AH * SW)          // 680 vertical-sum points
#define NA (AH * AW)          // 660 A points
#define ITER_V ((NV + NT - 1) / NT)   // 3
#define ITER_A ((NA + NT - 1) / NT)   // 3

__device__ __forceinline__ double fast_rcp(double v) {
#if __has_builtin(__builtin_amdgcn_rcp)
    double r = __builtin_amdgcn_rcp(v);     // v_rcp_f64, ~29-bit
#else
    double r = 1.0 / v;
#endif
    double e = fma(-v, r, 1.0);             // Newton 1 -> ~53-bit
    r = fma(r, e, r);
    e = fma(-v, r, 1.0);                    // Newton 2 -> ~1 ulp
    r = fma(r, e, r);
    return r;
}

__device__ __forceinline__ int iclamp(int v, int lo, int hi) {
    return v < lo ? lo : (v > hi ? hi : v);
}

__global__ __launch_bounds__(NT, 7) void fgf_fused_kernel(
    const float* __restrict__ x, const float* __restrict__ y,
    float* __restrict__ out, int H, int W)
{
    // planes: 0=Sx, 1=Sy, 2=Sxy, 3=Sxx (vertical 3-row sums).
    // After stage 2b, planes 0/1 are reused (post-barrier) as A and b.
    __shared__ double sV[4][AH][SW];

    const int c   = blockIdx.z;
    const int ox0 = blockIdx.x * TX;
    const int oy0 = blockIdx.y * TY;
    const size_t plane = (size_t)H * (size_t)W;
    const float* xc = x + (size_t)c * plane;
    const float* yc = y + (size_t)c * plane;

    const int tx  = threadIdx.x;          // 0..63
    const int g   = threadIdx.y;          // 0..3
    const int tid = g * 64 + tx;
    const int r0  = g * STEPS;
    const int xg  = ox0 + tx;

    // ---- preload 'im' pixels for stage 3 (coalesced, hides under stage 2) ----
    float imf[STEPS];
#pragma unroll
    for (int s = 0; s < STEPS; s++) {
        int yg = iclamp(oy0 + r0 + s, 0, H - 1);
        int xp = iclamp(xg, 0, W - 1);
        imf[s] = xc[(size_t)yg * W + xp];
    }

    // ---- stage 2a: vertical 3-row column sums straight from global ----
#pragma unroll
    for (int it = 0; it < ITER_V; it++) {
        int i = tid + it * NT;
        if (i < NV) {
            int ly = i / SW, lx = i - ly * SW;
            int gx = iclamp(ox0 - 2 + lx, 0, W - 1);
            int gy = oy0 - 2 + ly;
            int g0 = iclamp(gy,     0, H - 1);
            int g1 = iclamp(gy + 1, 0, H - 1);
            int g2 = iclamp(gy + 2, 0, H - 1);
            size_t i0 = (size_t)g0 * W + gx;
            size_t i1 = (size_t)g1 * W + gx;
            size_t i2 = (size_t)g2 * W + gx;
            double x0 = (double)xc[i0], x1 = (double)xc[i1], x2 = (double)xc[i2];
            double y0 = (double)yc[i0], y1 = (double)yc[i1], y2 = (double)yc[i2];
            sV[0][ly][lx] = (x0 + x1) + x2;
            sV[1][ly][lx] = (y0 + y1) + y2;
            sV[2][ly][lx] = fma(x2, y2, fma(x1, y1, x0 * y0));
            sV[3][ly][lx] = fma(x2, x2, fma(x1, x1, x0 * x0));
        }
    }
    __syncthreads();

    // ---- stage 2b: horizontal finish -> A,b in regs; then alias-write ----
    const double EPS81 = 81.0 * 1.0e-4;
    const double INV9  = 1.0 / 9.0;
    double Abuf[ITER_A], Bbuf[ITER_A];
#pragma unroll
    for (int it = 0; it < ITER_A; it++) {
        int i = tid + it * NT;
        double Av = 0.0, Bv = 0.0;
        if (i < NA) {
            int ly = i / AW, lx = i - ly * AW;
            int ay = oy0 - 1 + ly;
            int ax = ox0 - 1 + lx;
            if (ay >= 0 && ay < H && ax >= 0 && ax < W) {
                double Sx  = (sV[0][ly][lx] + sV[0][ly][lx + 1]) + sV[0][ly][lx + 2];
                double Sy  = (sV[1][ly][lx] + sV[1][ly][lx + 1]) + sV[1][ly][lx + 2];
                double Sxy = (sV[2][ly][lx] + sV[2][ly][lx + 1]) + sV[2][ly][lx + 2];
                double Sxx = (sV[3][ly][lx] + sV[3][ly][lx + 1]) + sV[3][ly][lx + 2];
                double num = fma(9.0, Sxy, -(Sx * Sy));            // 9*cov*9
                double den = fma(-Sx, Sx, fma(9.0, Sxx, EPS81));   // 9*(var+eps)*9
                Av = num * fast_rcp(den);
                Bv = fma(-Av, Sx, Sy) * INV9;
            }
        }
        Abuf[it] = Av;
        Bbuf[it] = Bv;
    }
    __syncthreads();   // all reads of sV done before planes 0/1 are overwritten
#pragma unroll
    for (int it = 0; it < ITER_A; it++) {
        int i = tid + it * NT;
        if (i < NA) {
            int ly = i / AW, lx = i - ly * AW;
            sV[0][ly][lx] = Abuf[it];   // A
            sV[1][ly][lx] = Bbuf[it];   // b
        }
    }
    __syncthreads();

    double (*sA)[SW] = sV[0];
    double (*sB)[SW] = sV[1];

    // ---- stage 3: rolling pair-sum sliding window + argmin (fp64) ----
    // State per side: {L2=c0+c1, R2=c1+c2, F3=all3} at vertical levels
    //   t = A rows r-1..r, m = rows r..r+1, p = row r+1 (A-local r, r+1, r+2).
    // Directions: L=tL+pL, R=tR+pR, U=tF, D=mF, NW=tL, NE=tR, SW=mL, SE=mR.
    const double I6 = 1.0 / 6.0;
    const bool xok = (xg < W);

    double tLA, tRA, tFA, mLA, mRA, mFA, pLA, pRA, pFA;
    double tLB, tRB, tFB, mLB, mRB, mFB, pLB, pRB, pFB;
    {
        double a0 = sA[r0 + 0][tx], a1 = sA[r0 + 0][tx + 1], a2 = sA[r0 + 0][tx + 2];
        double L0 = a0 + a1, R0 = a1 + a2, F0 = L0 + a2;
        a0 = sA[r0 + 1][tx]; a1 = sA[r0 + 1][tx + 1]; a2 = sA[r0 + 1][tx + 2];
        double L1 = a0 + a1, R1 = a1 + a2, F1 = L1 + a2;
        a0 = sA[r0 + 2][tx]; a1 = sA[r0 + 2][tx + 1]; a2 = sA[r0 + 2][tx + 2];
        double L2 = a0 + a1, R2 = a1 + a2, F2 = L2 + a2;
        tLA = L0 + L1; tRA = R0 + R1; tFA = F0 + F1;
        mLA = L1 + L2; mRA = R1 + R2; mFA = F1 + F2;
        pLA = L2; pRA = R2; pFA = F2;

        double b0 = sB[r0 + 0][tx], b1 = sB[r0 + 0][tx + 1], b2 = sB[r0 + 0][tx + 2];
        double M0 = b0 + b1, S0 = b1 + b2, G0 = M0 + b2;
        b0 = sB[r0 + 1][tx]; b1 = sB[r0 + 1][tx + 1]; b2 = sB[r0 + 1][tx + 2];
        double M1 = b0 + b1, S1 = b1 + b2, G1 = M1 + b2;
        b0 = sB[r0 + 2][tx]; b1 = sB[r0 + 2][tx + 1]; b2 = sB[r0 + 2][tx + 2];
        double M2 = b0 + b1, S2 = b1 + b2, G2 = M2 + b2;
        tLB = M0 + M1; tRB = S0 + S1; tFB = G0 + G1;
        mLB = M1 + M2; mRB = S1 + S2; mFB = G1 + G2;
        pLB = M2; pRB = S2; pFB = G2;
    }

#pragma unroll
    for (int step = 0; step < STEPS; step++) {
        const int r  = r0 + step;
        const int yg = oy0 + r;
        if (xok && yg < H) {
            double im  = (double)imf[step];
            double mim = -im;

            // direction sums, order: L, R, U, D, NW, NE, SW, SE
            double sa[8] = { tLA + pLA, tRA + pRA, tFA, mFA, tLA, tRA, mLA, mRA };
            double sb[8] = { tLB + pLB, tRB + pRB, tFB, mFB, tLB, tRB, mLB, mRB };

            double best = 0.0;
#pragma unroll
            for (int k = 0; k < 8; k++) {
                double w = (k < 4) ? I6 : 0.25;
                double d = fma(w, fma(sa[k], im, sb[k]), mim);
                if (k == 0) best = d;
                else        best = (fabs(d) < fabs(best)) ? d : best;   // first-min tie order
            }

            double res = trunc(best + im);
            res = fmin(fmax(res, 0.0), 255.0);
            out[(size_t)c * plane + (size_t)yg * W + xg] = (float)res;
        }

        if (step < STEPS - 1) {
            // advance: new A-local row r+3; t <- m, m <- p + n, p <- n
            double n0 = sA[r + 3][tx], n1 = sA[r + 3][tx + 1], n2 = sA[r + 3][tx + 2];
            double nL = n0 + n1, nR = n1 + n2, nF = nL + n2;
            tLA = mLA; tRA = mRA; tFA = mFA;
            mLA = pLA + nL; mRA = pRA + nR; mFA = pFA + nF;
            pLA = nL; pRA = nR; pFA = nF;

            n0 = sB[r + 3][tx]; n1 = sB[r + 3][tx + 1]; n2 = sB[r + 3][tx + 2];
            nL = n0 + n1; nR = n1 + n2; nF = nL + n2;
            tLB = mLB; tRB = mRB; tFB = mFB;
            mLB = pLB + nL; mRB = pRB + nR; mFB = pFB + nF;
            pLB = nL; pRB = nR; pFB = nF;
        }
    }
}

extern "C" void kernel_launch(void* const* d_in, const int* in_sizes, int n_in,
                              void* d_out, int out_size, void* d_ws, size_t ws_size,
                              hipStream_t stream) {
    const float* lr_x = (const float*)d_in[0];
    const float* lr_y = (const float*)d_in[1];
    // d_in[2] (hr_x) is dead in the reference computation.
    float* out = (float*)d_out;

    const int plane = in_sizes[0] / 3;
    const int H = (int)(0.5 + sqrt((double)plane));
    const int W = plane / H;

    dim3 block(64, 4, 1);
    dim3 grid((W + TX - 1) / TX, (H + TY - 1) / TY, 3);
    fgf_fused_kernel<<<grid, block, 0, stream>>>(lr_x, lr_y, out, H, W);
}